// Round 1
// baseline (675.418 us; speedup 1.0000x reference)
//
#include <hip/hip_runtime.h>
#include <hip/hip_bf16.h>
#include <math.h>

// Problem: B=256, S=196, D=2048, H=512
//   att_h  = h @ W_h2att^T + b_h2att              [B,H]
//   scores = sum_h tanh(p_att + att_h) * w_alpha  [B,S]
//   weight = renorm(softmax(scores) * mask)       [B,S]
//   out    = sum_s weight * att_feats             [B,D]

#define B_ 256
#define S_ 196
#define D_ 2048
#define H_ 512

// ---------------------------------------------------------------------------
// Kernel 1: att_h[b,j] = sum_d h[b,d] * W[j,d] + bias[j]
// NT GEMM, M=256, N=512, K=2048. 32x32 tiles, BK=32, 256 threads, 2x2/thread.
// ---------------------------------------------------------------------------
__global__ __launch_bounds__(256) void h2att_kernel(
    const float* __restrict__ h, const float* __restrict__ W,
    const float* __restrict__ bias, float* __restrict__ att_h) {
  __shared__ float lds_a[32][33];
  __shared__ float lds_b[32][33];

  const int tid = threadIdx.x;
  const int m0 = blockIdx.y * 32;   // over B
  const int n0 = blockIdx.x * 32;   // over H

  const int lr = tid >> 3;          // 0..31 row for loading
  const int lc = (tid & 7) * 4;     // 0..28 col4 for loading
  const int tm = tid >> 4;          // 0..15
  const int tn = tid & 15;          // 0..15

  float acc00 = 0.f, acc01 = 0.f, acc10 = 0.f, acc11 = 0.f;

  for (int k0 = 0; k0 < D_; k0 += 32) {
    float4 av = *(const float4*)(h + (size_t)(m0 + lr) * D_ + k0 + lc);
    float4 bv = *(const float4*)(W + (size_t)(n0 + lr) * D_ + k0 + lc);
    __syncthreads();
    lds_a[lr][lc + 0] = av.x; lds_a[lr][lc + 1] = av.y;
    lds_a[lr][lc + 2] = av.z; lds_a[lr][lc + 3] = av.w;
    lds_b[lr][lc + 0] = bv.x; lds_b[lr][lc + 1] = bv.y;
    lds_b[lr][lc + 2] = bv.z; lds_b[lr][lc + 3] = bv.w;
    __syncthreads();
#pragma unroll
    for (int kk = 0; kk < 32; ++kk) {
      float a0 = lds_a[tm][kk];
      float a1 = lds_a[tm + 16][kk];
      float b0 = lds_b[tn][kk];
      float b1 = lds_b[tn + 16][kk];
      acc00 = fmaf(a0, b0, acc00);
      acc01 = fmaf(a0, b1, acc01);
      acc10 = fmaf(a1, b0, acc10);
      acc11 = fmaf(a1, b1, acc11);
    }
  }

  const int m = m0 + tm, n = n0 + tn;
  float bn0 = bias[n], bn1 = bias[n + 16];
  att_h[(size_t)m * H_ + n]              = acc00 + bn0;
  att_h[(size_t)m * H_ + n + 16]         = acc01 + bn1;
  att_h[(size_t)(m + 16) * H_ + n]       = acc10 + bn0;
  att_h[(size_t)(m + 16) * H_ + n + 16]  = acc11 + bn1;
}

// ---------------------------------------------------------------------------
// Kernel 2: scores[b,s] = sum_h tanh(p[b,s,h] + att_h[b,h]) * w_alpha[h] + b_a
// One wave (64 lanes) per (b,s). 4 waves / block.
// ---------------------------------------------------------------------------
__global__ __launch_bounds__(256) void scores_kernel(
    const float* __restrict__ p, const float* __restrict__ att_h,
    const float* __restrict__ w_alpha, const float* __restrict__ b_alpha,
    float* __restrict__ scores) {
  const int wave = threadIdx.x >> 6;
  const int lane = threadIdx.x & 63;
  const int idx = blockIdx.x * 4 + wave;   // 0 .. B*S-1  (exact: 12544*4=50176)
  const int b = idx / S_;

  const float* pp = p + (size_t)idx * H_;
  const float* ah = att_h + (size_t)b * H_;

  float acc = 0.f;
#pragma unroll
  for (int h0 = 0; h0 < H_; h0 += 256) {
    const int o = h0 + lane * 4;
    float4 pv = *(const float4*)(pp + o);
    float4 av = *(const float4*)(ah + o);
    float4 wv = *(const float4*)(w_alpha + o);
    acc += tanhf(pv.x + av.x) * wv.x;
    acc += tanhf(pv.y + av.y) * wv.y;
    acc += tanhf(pv.z + av.z) * wv.z;
    acc += tanhf(pv.w + av.w) * wv.w;
  }
#pragma unroll
  for (int off = 32; off > 0; off >>= 1) acc += __shfl_down(acc, off);
  if (lane == 0) scores[idx] = acc + b_alpha[0];
}

// ---------------------------------------------------------------------------
// Kernel 3: per-b softmax (masked renorm) + weighted sum over att_feats.
// grid = (D/1024, B); block = 256 threads, 4 floats (float4) per thread.
// ---------------------------------------------------------------------------
__global__ __launch_bounds__(256) void attres_kernel(
    const float* __restrict__ scores, const float* __restrict__ mask,
    const float* __restrict__ att_feats, float* __restrict__ out) {
  __shared__ float w_lds[S_];
  __shared__ float red[4];

  const int tid = threadIdx.x;
  const int b = blockIdx.y;
  const int wave = tid >> 6, lane = tid & 63;

  // ---- softmax over S=196 (threads 196..255 idle-padded) ----
  float sc = (tid < S_) ? scores[(size_t)b * S_ + tid] : -INFINITY;

  // block max
  float v = sc;
#pragma unroll
  for (int off = 32; off > 0; off >>= 1) v = fmaxf(v, __shfl_down(v, off));
  if (lane == 0) red[wave] = v;
  __syncthreads();
  float mx = fmaxf(fmaxf(red[0], red[1]), fmaxf(red[2], red[3]));
  __syncthreads();

  float e = (tid < S_) ? expf(sc - mx) : 0.f;

  // block sum of e
  v = e;
#pragma unroll
  for (int off = 32; off > 0; off >>= 1) v += __shfl_down(v, off);
  if (lane == 0) red[wave] = v;
  __syncthreads();
  float z = red[0] + red[1] + red[2] + red[3];
  __syncthreads();

  float w = (tid < S_) ? (e / z) * mask[(size_t)b * S_ + tid] : 0.f;

  // block sum of w (renorm)
  v = w;
#pragma unroll
  for (int off = 32; off > 0; off >>= 1) v += __shfl_down(v, off);
  if (lane == 0) red[wave] = v;
  __syncthreads();
  float z2 = red[0] + red[1] + red[2] + red[3];

  if (tid < S_) w_lds[tid] = w / z2;
  __syncthreads();

  // ---- weighted sum: out[b, d0..d0+3] ----
  const int d0 = blockIdx.x * 1024 + tid * 4;
  const float* base = att_feats + (size_t)b * S_ * D_ + d0;

  float4 acc = {0.f, 0.f, 0.f, 0.f};
#pragma unroll 4
  for (int s = 0; s < S_; ++s) {
    float ws = w_lds[s];
    float4 vv = *(const float4*)(base + (size_t)s * D_);
    acc.x = fmaf(ws, vv.x, acc.x);
    acc.y = fmaf(ws, vv.y, acc.y);
    acc.z = fmaf(ws, vv.z, acc.z);
    acc.w = fmaf(ws, vv.w, acc.w);
  }
  *(float4*)(out + (size_t)b * D_ + d0) = acc;
}

// ---------------------------------------------------------------------------
extern "C" void kernel_launch(void* const* d_in, const int* in_sizes, int n_in,
                              void* d_out, int out_size, void* d_ws, size_t ws_size,
                              hipStream_t stream) {
  const float* h         = (const float*)d_in[0];   // [B,D]
  const float* att_feats = (const float*)d_in[1];   // [B,S,D]
  const float* p_att     = (const float*)d_in[2];   // [B,S,H]
  const float* att_masks = (const float*)d_in[3];   // [B,S]
  const float* W_h2att   = (const float*)d_in[4];   // [H,D]
  const float* b_h2att   = (const float*)d_in[5];   // [H]
  const float* w_alpha   = (const float*)d_in[6];   // [H]
  const float* b_alpha   = (const float*)d_in[7];   // [1]
  float* out = (float*)d_out;                       // [B,D]

  float* att_h  = (float*)d_ws;                 // B*H   = 131072 floats
  float* scores = att_h + (size_t)B_ * H_;      // B*S   = 50176 floats

  // K1: att_h
  dim3 g1(H_ / 32, B_ / 32);   // (16, 8) = 128 blocks
  h2att_kernel<<<g1, 256, 0, stream>>>(h, W_h2att, b_h2att, att_h);

  // K2: scores  (B*S/4 = 12544 blocks)
  scores_kernel<<<(B_ * S_) / 4, 256, 0, stream>>>(p_att, att_h, w_alpha,
                                                   b_alpha, scores);

  // K3: softmax + weighted sum
  dim3 g3(D_ / 1024, B_);      // (2, 256) = 512 blocks
  attres_kernel<<<g3, 256, 0, stream>>>(scores, att_masks, att_feats, out);
}